// Round 1
// baseline (3336.197 us; speedup 1.0000x reference)
//
#include <hip/hip_runtime.h>

#define B_   8
#define C_   128
#define HW_  128
#define KW_  9
#define BLKS 4               // blocks per batch (pos split)
#define POSB 32              // positions per block
#define ROWS 40              // 4 halo + 32 own + 4 halo
#define STRD 136             // LDS pos stride (elems)
#define BUFE (ROWS * STRD)   // 5440 elems per buffer
#define THREADS 256          // 4 waves; 1 wave/SIMD -> 512-reg budget for Q=2 weights

typedef __bf16 bf16x8 __attribute__((ext_vector_type(8)));
typedef float  floatx4 __attribute__((ext_vector_type(4)));
typedef unsigned long long u64;

__device__ __forceinline__ unsigned short bf16rn(float f) {
  union { float f; unsigned u; } x; x.f = f;
  return (unsigned short)((x.u + 0x7fffu + ((x.u >> 16) & 1u)) >> 16);
}

// ---------------- prologue: x (B,C,H,W) -> y (B,H,W,C) fp32 ------------------
__global__ __launch_bounds__(256) void nchw_to_nhwc(const float* __restrict__ x,
                                                    float* __restrict__ y) {
  __shared__ float tile[32][33];
  const int blk = blockIdx.x;
  const int b = blk >> 7, h = blk & 127;
  const int tx = threadIdx.x & 31, ty = threadIdx.x >> 5;
  for (int t = 0; t < 16; ++t) {
    const int c0 = (t >> 2) * 32, w0 = (t & 3) * 32;
#pragma unroll
    for (int i = 0; i < 4; ++i) {
      const int c = c0 + ty + i * 8;
      tile[ty + i * 8][tx] = x[(((long)b * C_ + c) * HW_ + h) * HW_ + w0 + tx];
    }
    __syncthreads();
#pragma unroll
    for (int i = 0; i < 4; ++i) {
      const int w = w0 + ty + i * 8;
      y[(((long)b * HW_ + h) * HW_ + w) * C_ + c0 + tx] = tile[tx][ty + i * 8];
    }
    __syncthreads();
  }
}

// ---------------- epilogue: y (B,H,W,C) -> out (B,C,H,W) ---------------------
__global__ __launch_bounds__(256) void nhwc_to_nchw(const float* __restrict__ y,
                                                    float* __restrict__ out) {
  __shared__ float tile[32][33];
  const int blk = blockIdx.x;
  const int b = blk >> 7, h = blk & 127;
  const int tx = threadIdx.x & 31, ty = threadIdx.x >> 5;
  for (int t = 0; t < 16; ++t) {
    const int w0 = (t >> 2) * 32, c0 = (t & 3) * 32;
#pragma unroll
    for (int i = 0; i < 4; ++i) {
      const int w = w0 + ty + i * 8;
      tile[ty + i * 8][tx] = y[(((long)b * HW_ + h) * HW_ + w) * C_ + c0 + tx];
    }
    __syncthreads();
#pragma unroll
    for (int i = 0; i < 4; ++i) {
      const int c = c0 + ty + i * 8;
      out[(((long)b * C_ + c) * HW_ + h) * HW_ + w0 + tx] = tile[tx][ty + i * 8];
    }
    __syncthreads();
  }
}

// ---------------- per-direction scan: 32 blocks = 8 batch x 4 pos-chunks -----
// 4 waves/block, 1 wave/SIMD. Each wave owns TWO co-tiles (co0 = wave*16 + ct*64)
// so every LDS B-fragment read feeds 2 MFMAs -> per-CU LDS traffic halves.
// Halo/flags via RELAXED agent atomics only (cache-bypass); __syncthreads drains
// vmcnt(0) so mailbox stores are at the coherence point before tid0's flag store.
__global__ __launch_bounds__(THREADS, 1) void scnn_scan_dir(
    const float* __restrict__ Kg, float* __restrict__ y,
    int* flags, u64* mb,
    const int posStride, const int sStride, const int s0, const int ds,
    const int dirIdx) {
  __shared__ unsigned short prow[2][BUFE];
  const int tid = threadIdx.x;
  const int bid = blockIdx.x;
  const int batch = bid & 7;
  const int blk = bid >> 3;
  const int p0 = blk * POSB;
  const int lane = tid & 63;
  const int wave = tid >> 6;           // 0..3
  const int l15 = lane & 15;
  const int quad = lane >> 4;
  const int ybase = batch * (HW_ * HW_ * C_);
  int* flagB = flags + (dirIdx * 8 + batch) * BLKS;

  // zero both LDS buffers (halo rows must read 0 for zero-pad conv)
  for (int i = tid; i < 2 * BUFE / 4; i += THREADS)
    ((u64*)prow)[i] = 0ull;

  // persistent weights, A-operand (m = co_local): 2 co-tiles x 36 frags = 288 VGPRs
  bf16x8 wfrag[2][KW_][4];
#pragma unroll
  for (int ct = 0; ct < 2; ++ct) {
    const int co0 = wave * 16 + ct * 64;
#pragma unroll
    for (int kw = 0; kw < KW_; ++kw)
#pragma unroll
      for (int c4 = 0; c4 < 4; ++c4) {
        union { bf16x8 v; unsigned short u[8]; } t;
#pragma unroll
        for (int j = 0; j < 8; ++j)
          t.u[j] = bf16rn(Kg[(kw * 128 + c4 * 32 + quad * 8 + j) * 128 + co0 + l15]);
        wfrag[ct][kw][c4] = t.v;
      }
  }
  __syncthreads();

  // init: load first row (s0) 40-pos window (incl halo) from y -> buffer 0
  for (int i = tid; i < ROWS * 32; i += THREADS) {
    const int row = i >> 5, cg = i & 31;
    const int pos = p0 - 4 + row;
    if (pos >= 0 && pos < HW_) {
      const floatx4 v =
          *(const floatx4*)&y[ybase + s0 * sStride + pos * posStride + cg * 4];
      union { u64 u; unsigned short s[4]; } t;
      t.s[0] = bf16rn(v[0]); t.s[1] = bf16rn(v[1]);
      t.s[2] = bf16rn(v[2]); t.s[3] = bf16rn(v[3]);
      *(u64*)&prow[0][row * STRD + cg * 4] = t.u;
    }
  }
  __syncthreads();

  int pb = 0;
#pragma unroll 1
  for (int s = 1; s < HW_; ++s) {
    const int srow = s0 + s * ds;
    const int rowb = ybase + srow * sStride;

    __syncthreads();  // A: drains vmcnt -> step s-1 stores (incl mailbox) visible
    if (tid == 0)
      __hip_atomic_store(&flagB[blk], s - 1, __ATOMIC_RELAXED,
                         __HIP_MEMORY_SCOPE_AGENT);
    if (s >= 2) {
      if (tid == 0 && blk > 0)
        while (__hip_atomic_load(&flagB[blk - 1], __ATOMIC_RELAXED,
                                 __HIP_MEMORY_SCOPE_AGENT) < s - 1)
          __builtin_amdgcn_s_sleep(1);
      if (tid == 1 && blk < BLKS - 1)
        while (__hip_atomic_load(&flagB[blk + 1], __ATOMIC_RELAXED,
                                 __HIP_MEMORY_SCOPE_AGENT) < s - 1)
          __builtin_amdgcn_s_sleep(1);
      __syncthreads();  // P: poll done
      __atomic_signal_fence(__ATOMIC_SEQ_CST);
      const int par = (s - 1) & 1;
      {
        const int side = tid >> 7, p = (tid >> 5) & 3, cg = tid & 31;
        const bool doit = side ? (blk < BLKS - 1) : (blk > 0);
        if (doit) {
          const int srcB = side ? (blk + 1) : (blk - 1);
          const int srcSide = side ? 0 : 1;  // right halo = right nbr's L edge
          const int mbi =
              ((((batch * BLKS + srcB) * 2 + srcSide) * 2 + par) * 4 + p) * 32 + cg;
          const u64 v =
              __hip_atomic_load(&mb[mbi], __ATOMIC_RELAXED, __HIP_MEMORY_SCOPE_AGENT);
          const int row = side ? (36 + p) : p;
          *(u64*)&prow[pb][row * STRD + cg * 4] = v;
        }
      }
    }
    __syncthreads();  // B: halo in LDS; prev buffer complete

    // cur-row prefetch (independent of prev row; overlaps the k-loop)
    floatx4 cur[2][2];
#pragma unroll
    for (int ct = 0; ct < 2; ++ct)
#pragma unroll
      for (int n = 0; n < 2; ++n)
        cur[ct][n] = *(const floatx4*)&y[rowb + (p0 + n * 16 + l15) * posStride +
                                         wave * 16 + ct * 64 + quad * 4];

    floatx4 acc[2][2];
#pragma unroll
    for (int ct = 0; ct < 2; ++ct)
#pragma unroll
      for (int n = 0; n < 2; ++n)
        acc[ct][n] = floatx4{0.f, 0.f, 0.f, 0.f};

    const unsigned short* pbase = &prow[pb][l15 * STRD + quad * 8];
#pragma unroll
    for (int kw = 0; kw < KW_; ++kw)
#pragma unroll
      for (int c4 = 0; c4 < 4; ++c4) {
        const bf16x8 b0 = *(const bf16x8*)(pbase + kw * STRD + c4 * 32);
        const bf16x8 b1 = *(const bf16x8*)(pbase + (kw + 16) * STRD + c4 * 32);
        acc[0][0] = __builtin_amdgcn_mfma_f32_16x16x32_bf16(wfrag[0][kw][c4], b0,
                                                            acc[0][0], 0, 0, 0);
        acc[0][1] = __builtin_amdgcn_mfma_f32_16x16x32_bf16(wfrag[0][kw][c4], b1,
                                                            acc[0][1], 0, 0, 0);
        acc[1][0] = __builtin_amdgcn_mfma_f32_16x16x32_bf16(wfrag[1][kw][c4], b0,
                                                            acc[1][0], 0, 0, 0);
        acc[1][1] = __builtin_amdgcn_mfma_f32_16x16x32_bf16(wfrag[1][kw][c4], b1,
                                                            acc[1][1], 0, 0, 0);
      }

    // epilogue: o = cur + relu(acc); fp32 -> y, bf16 -> nxt LDS (+ mailbox)
    unsigned short* nxt = prow[pb ^ 1];
    const int par_w = s & 1;
#pragma unroll
    for (int ct = 0; ct < 2; ++ct) {
      const int co0 = wave * 16 + ct * 64;
#pragma unroll
      for (int n = 0; n < 2; ++n) {
        const int pl = n * 16 + l15;           // local pos 0..31
        const int co = co0 + quad * 4;
        const floatx4 a = acc[ct][n];
        const floatx4 c = cur[ct][n];
        floatx4 o;
        o[0] = c[0] + (a[0] > 0.f ? a[0] : 0.f);
        o[1] = c[1] + (a[1] > 0.f ? a[1] : 0.f);
        o[2] = c[2] + (a[2] > 0.f ? a[2] : 0.f);
        o[3] = c[3] + (a[3] > 0.f ? a[3] : 0.f);
        *(floatx4*)&y[rowb + (p0 + pl) * posStride + co] = o;
        union { u64 u; unsigned short s[4]; } t;
        t.s[0] = bf16rn(o[0]); t.s[1] = bf16rn(o[1]);
        t.s[2] = bf16rn(o[2]); t.s[3] = bf16rn(o[3]);
        *(u64*)&nxt[(pl + 4) * STRD + co] = t.u;
        // boundary pos -> mailbox (relaxed agent atomics, bypass path)
        if (n == 0 && l15 < 4 && blk > 0) {
          const int mbi =
              ((((batch * BLKS + blk) * 2 + 0) * 2 + par_w) * 4 + l15) * 32 +
              (wave * 4 + ct * 16 + quad);
          __hip_atomic_store(&mb[mbi], t.u, __ATOMIC_RELAXED,
                             __HIP_MEMORY_SCOPE_AGENT);
        }
        if (n == 1 && l15 >= 12 && blk < BLKS - 1) {
          const int mbi =
              ((((batch * BLKS + blk) * 2 + 1) * 2 + par_w) * 4 + (l15 - 12)) * 32 +
              (wave * 4 + ct * 16 + quad);
          __hip_atomic_store(&mb[mbi], t.u, __ATOMIC_RELAXED,
                             __HIP_MEMORY_SCOPE_AGENT);
        }
      }
    }
    pb ^= 1;
  }
}

// ---------------- launcher ---------------------------------------------------
extern "C" void kernel_launch(void* const* d_in, const int* in_sizes, int n_in,
                              void* d_out, int out_size, void* d_ws, size_t ws_size,
                              hipStream_t stream) {
  const float* x = (const float*)d_in[0];
  const float* K[4] = {(const float*)d_in[1], (const float*)d_in[2],
                       (const float*)d_in[3], (const float*)d_in[4]};
  float* out = (float*)d_out;

  char* ws = (char*)d_ws;
  float* y = (float*)ws;                       // 67,108,864 B
  int* flags = (int*)(ws + 67108864);          // 4*8*4 ints = 512 B
  u64* mb = (u64*)(ws + 67108864 + 1024);      // 8*4*2*2*4*128 bf16 = 262144 B

  hipMemsetAsync(flags, 0, 1024, stream);
  nchw_to_nhwc<<<B_ * HW_, 256, 0, stream>>>(x, y);

  const int PS[4] = {C_, C_, HW_ * C_, HW_ * C_};
  const int SS[4] = {HW_ * C_, HW_ * C_, C_, C_};
  const int S0[4] = {0, HW_ - 1, 0, HW_ - 1};
  const int DS[4] = {1, -1, 1, -1};
  for (int d = 0; d < 4; ++d)
    scnn_scan_dir<<<B_ * BLKS, THREADS, 0, stream>>>(K[d], y, flags, mb, PS[d],
                                                     SS[d], S0[d], DS[d], d);

  nhwc_to_nchw<<<B_ * HW_, 256, 0, stream>>>(y, out);
}

// Round 2
// 2221.954 us; speedup vs baseline: 1.5015x; 1.5015x over previous
//
#include <hip/hip_runtime.h>

#define B_   8
#define C_   128
#define HW_  128
#define KW_  9
#define BLKS 4               // blocks per batch (pos split)
#define POSB 32              // positions per block
#define ROWS 40              // 4 halo + 32 own + 4 halo
#define STRD 136             // LDS pos stride (elems)
#define BUFE (ROWS * STRD)   // 5440 elems per buffer
#define THREADS 512          // 8 waves, 2/SIMD

typedef __bf16 bf16x8 __attribute__((ext_vector_type(8)));
typedef float  floatx4 __attribute__((ext_vector_type(4)));
typedef unsigned long long u64;

__device__ __forceinline__ unsigned short bf16rn(float f) {
  union { float f; unsigned u; } x; x.f = f;
  return (unsigned short)((x.u + 0x7fffu + ((x.u >> 16) & 1u)) >> 16);
}

// ---------------- prologue: x (B,C,H,W) -> y (B,H,W,C) fp32 ------------------
__global__ __launch_bounds__(256) void nchw_to_nhwc(const float* __restrict__ x,
                                                    float* __restrict__ y) {
  __shared__ float tile[32][33];
  const int blk = blockIdx.x;
  const int b = blk >> 7, h = blk & 127;
  const int tx = threadIdx.x & 31, ty = threadIdx.x >> 5;
  for (int t = 0; t < 16; ++t) {
    const int c0 = (t >> 2) * 32, w0 = (t & 3) * 32;
#pragma unroll
    for (int i = 0; i < 4; ++i) {
      const int c = c0 + ty + i * 8;
      tile[ty + i * 8][tx] = x[(((long)b * C_ + c) * HW_ + h) * HW_ + w0 + tx];
    }
    __syncthreads();
#pragma unroll
    for (int i = 0; i < 4; ++i) {
      const int w = w0 + ty + i * 8;
      y[(((long)b * HW_ + h) * HW_ + w) * C_ + c0 + tx] = tile[tx][ty + i * 8];
    }
    __syncthreads();
  }
}

// ---------------- epilogue: y (B,H,W,C) -> out (B,C,H,W) ---------------------
__global__ __launch_bounds__(256) void nhwc_to_nchw(const float* __restrict__ y,
                                                    float* __restrict__ out) {
  __shared__ float tile[32][33];
  const int blk = blockIdx.x;
  const int b = blk >> 7, h = blk & 127;
  const int tx = threadIdx.x & 31, ty = threadIdx.x >> 5;
  for (int t = 0; t < 16; ++t) {
    const int w0 = (t >> 2) * 32, c0 = (t & 3) * 32;
#pragma unroll
    for (int i = 0; i < 4; ++i) {
      const int w = w0 + ty + i * 8;
      tile[ty + i * 8][tx] = y[(((long)b * HW_ + h) * HW_ + w) * C_ + c0 + tx];
    }
    __syncthreads();
#pragma unroll
    for (int i = 0; i < 4; ++i) {
      const int c = c0 + ty + i * 8;
      out[(((long)b * C_ + c) * HW_ + h) * HW_ + w0 + tx] = tile[tx][ty + i * 8];
    }
    __syncthreads();
  }
}

// ---------------- per-direction scan: 32 blocks = 8 batch x 4 pos-chunks -----
// 8 waves (2/SIMD). wave w = (kh = w>>2, co2 = w&3). Each wave computes TWO
// co-tiles (co2*16, co2*16+64) over HALF the K-fragments (c4 in {2kh, 2kh+1}):
// weights stay at 144 VGPR/wave (fits 2 waves/SIMD), LDS B-frag reads halve
// (576 -> 288 b128 per block-row). kh=1 waves write fp32 partials to LDS
// scratch; kh=0 waves reduce and run the epilogue.
// Halo/flags via RELAXED agent atomics only; __syncthreads drains vmcnt(0) so
// mailbox stores are at the coherence point before tid0's relaxed flag store.
__global__ __launch_bounds__(THREADS, 2) void scnn_scan_dir(
    const float* __restrict__ Kg, float* __restrict__ y,
    int* flags, u64* mb,
    const int posStride, const int sStride, const int s0, const int ds,
    const int dirIdx) {
  __shared__ unsigned short prow[2][BUFE];
  __shared__ float scratch[4 * 2 * 2 * 64 * 4];  // [co2][ct][n][lane][4] = 16 KB
  const int tid = threadIdx.x;
  const int bid = blockIdx.x;
  const int batch = bid & 7;
  const int blk = bid >> 3;
  const int p0 = blk * POSB;
  const int lane = tid & 63;
  const int wave = tid >> 6;           // 0..7
  const int kh = wave >> 2;            // K-half: c4 in {2kh, 2kh+1}
  const int co2 = wave & 3;            // co-tile pair index
  const int l15 = lane & 15;
  const int quad = lane >> 4;
  const int ybase = batch * (HW_ * HW_ * C_);
  int* flagB = flags + (dirIdx * 8 + batch) * BLKS;

  // zero both LDS buffers (halo rows must read 0 for zero-pad conv)
  for (int i = tid; i < 2 * BUFE / 4; i += THREADS)
    ((u64*)prow)[i] = 0ull;

  // persistent weights, A-operand (m = co_local): 2 ct x 9 kw x 2 c2 = 144 VGPRs
  bf16x8 wfrag[2][KW_][2];
#pragma unroll
  for (int ct = 0; ct < 2; ++ct) {
    const int co0 = co2 * 16 + ct * 64;
#pragma unroll
    for (int kw = 0; kw < KW_; ++kw)
#pragma unroll
      for (int c2 = 0; c2 < 2; ++c2) {
        const int c4 = kh * 2 + c2;
        union { bf16x8 v; unsigned short u[8]; } t;
#pragma unroll
        for (int j = 0; j < 8; ++j)
          t.u[j] = bf16rn(Kg[(kw * 128 + c4 * 32 + quad * 8 + j) * 128 + co0 + l15]);
        wfrag[ct][kw][c2] = t.v;
      }
  }
  __syncthreads();

  // init: load first row (s0) 40-pos window (incl halo) from y -> buffer 0
  for (int i = tid; i < ROWS * 32; i += THREADS) {
    const int row = i >> 5, cg = i & 31;
    const int pos = p0 - 4 + row;
    if (pos >= 0 && pos < HW_) {
      const floatx4 v =
          *(const floatx4*)&y[ybase + s0 * sStride + pos * posStride + cg * 4];
      union { u64 u; unsigned short s[4]; } t;
      t.s[0] = bf16rn(v[0]); t.s[1] = bf16rn(v[1]);
      t.s[2] = bf16rn(v[2]); t.s[3] = bf16rn(v[3]);
      *(u64*)&prow[0][row * STRD + cg * 4] = t.u;
    }
  }
  __syncthreads();

  int pb = 0;
#pragma unroll 1
  for (int s = 1; s < HW_; ++s) {
    const int srow = s0 + s * ds;
    const int rowb = ybase + srow * sStride;

    __syncthreads();  // A: drains vmcnt -> step s-1 stores (incl mailbox) visible
    if (tid == 0)
      __hip_atomic_store(&flagB[blk], s - 1, __ATOMIC_RELAXED,
                         __HIP_MEMORY_SCOPE_AGENT);
    if (s >= 2) {
      if (tid == 0 && blk > 0)
        while (__hip_atomic_load(&flagB[blk - 1], __ATOMIC_RELAXED,
                                 __HIP_MEMORY_SCOPE_AGENT) < s - 1)
          __builtin_amdgcn_s_sleep(1);
      if (tid == 1 && blk < BLKS - 1)
        while (__hip_atomic_load(&flagB[blk + 1], __ATOMIC_RELAXED,
                                 __HIP_MEMORY_SCOPE_AGENT) < s - 1)
          __builtin_amdgcn_s_sleep(1);
      __syncthreads();  // P: poll done
      __atomic_signal_fence(__ATOMIC_SEQ_CST);
      const int par = (s - 1) & 1;
      if (tid < 256) {
        const int side = tid >> 7, p = (tid >> 5) & 3, cg = tid & 31;
        const bool doit = side ? (blk < BLKS - 1) : (blk > 0);
        if (doit) {
          const int srcB = side ? (blk + 1) : (blk - 1);
          const int srcSide = side ? 0 : 1;  // right halo = right nbr's L edge
          const int mbi =
              ((((batch * BLKS + srcB) * 2 + srcSide) * 2 + par) * 4 + p) * 32 + cg;
          const u64 v =
              __hip_atomic_load(&mb[mbi], __ATOMIC_RELAXED, __HIP_MEMORY_SCOPE_AGENT);
          const int row = side ? (36 + p) : p;
          *(u64*)&prow[pb][row * STRD + cg * 4] = v;
        }
      }
    }
    __syncthreads();  // B: halo in LDS; prev buffer complete

    // cur-row prefetch (finisher waves only; overlaps the k-loop)
    floatx4 cur[2][2];
    if (kh == 0) {
#pragma unroll
      for (int ct = 0; ct < 2; ++ct)
#pragma unroll
        for (int n = 0; n < 2; ++n)
          cur[ct][n] = *(const floatx4*)&y[rowb + (p0 + n * 16 + l15) * posStride +
                                           co2 * 16 + ct * 64 + quad * 4];
    }

    floatx4 acc[2][2];
#pragma unroll
    for (int ct = 0; ct < 2; ++ct)
#pragma unroll
      for (int n = 0; n < 2; ++n)
        acc[ct][n] = floatx4{0.f, 0.f, 0.f, 0.f};

    const unsigned short* pbase = &prow[pb][l15 * STRD + quad * 8];
#pragma unroll
    for (int kw = 0; kw < KW_; ++kw)
#pragma unroll
      for (int c2 = 0; c2 < 2; ++c2) {
        const int c4 = kh * 2 + c2;
        const bf16x8 b0 = *(const bf16x8*)(pbase + kw * STRD + c4 * 32);
        const bf16x8 b1 = *(const bf16x8*)(pbase + (kw + 16) * STRD + c4 * 32);
        acc[0][0] = __builtin_amdgcn_mfma_f32_16x16x32_bf16(wfrag[0][kw][c2], b0,
                                                            acc[0][0], 0, 0, 0);
        acc[0][1] = __builtin_amdgcn_mfma_f32_16x16x32_bf16(wfrag[0][kw][c2], b1,
                                                            acc[0][1], 0, 0, 0);
        acc[1][0] = __builtin_amdgcn_mfma_f32_16x16x32_bf16(wfrag[1][kw][c2], b0,
                                                            acc[1][0], 0, 0, 0);
        acc[1][1] = __builtin_amdgcn_mfma_f32_16x16x32_bf16(wfrag[1][kw][c2], b1,
                                                            acc[1][1], 0, 0, 0);
      }

    // K-half reduction: kh=1 writes partials, kh=0 adds them
    if (kh == 1) {
#pragma unroll
      for (int ct = 0; ct < 2; ++ct)
#pragma unroll
        for (int n = 0; n < 2; ++n)
          *(floatx4*)&scratch[(((co2 * 2 + ct) * 2 + n) * 64 + lane) * 4] =
              acc[ct][n];
    }
    __syncthreads();  // C: partials visible

    if (kh == 0) {
#pragma unroll
      for (int ct = 0; ct < 2; ++ct)
#pragma unroll
        for (int n = 0; n < 2; ++n) {
          const floatx4 pz =
              *(const floatx4*)&scratch[(((co2 * 2 + ct) * 2 + n) * 64 + lane) * 4];
          acc[ct][n] += pz;
        }

      // epilogue: o = cur + relu(acc); fp32 -> y, bf16 -> nxt LDS (+ mailbox)
      unsigned short* nxt = prow[pb ^ 1];
      const int par_w = s & 1;
#pragma unroll
      for (int ct = 0; ct < 2; ++ct) {
        const int co0 = co2 * 16 + ct * 64;
#pragma unroll
        for (int n = 0; n < 2; ++n) {
          const int pl = n * 16 + l15;           // local pos 0..31
          const int co = co0 + quad * 4;
          const floatx4 a = acc[ct][n];
          const floatx4 c = cur[ct][n];
          floatx4 o;
          o[0] = c[0] + (a[0] > 0.f ? a[0] : 0.f);
          o[1] = c[1] + (a[1] > 0.f ? a[1] : 0.f);
          o[2] = c[2] + (a[2] > 0.f ? a[2] : 0.f);
          o[3] = c[3] + (a[3] > 0.f ? a[3] : 0.f);
          *(floatx4*)&y[rowb + (p0 + pl) * posStride + co] = o;
          union { u64 u; unsigned short s[4]; } t;
          t.s[0] = bf16rn(o[0]); t.s[1] = bf16rn(o[1]);
          t.s[2] = bf16rn(o[2]); t.s[3] = bf16rn(o[3]);
          *(u64*)&nxt[(pl + 4) * STRD + co] = t.u;
          // boundary pos -> mailbox (relaxed agent atomics, bypass path)
          if (n == 0 && l15 < 4 && blk > 0) {
            const int mbi =
                ((((batch * BLKS + blk) * 2 + 0) * 2 + par_w) * 4 + l15) * 32 +
                (co2 * 4 + ct * 16 + quad);
            __hip_atomic_store(&mb[mbi], t.u, __ATOMIC_RELAXED,
                               __HIP_MEMORY_SCOPE_AGENT);
          }
          if (n == 1 && l15 >= 12 && blk < BLKS - 1) {
            const int mbi =
                ((((batch * BLKS + blk) * 2 + 1) * 2 + par_w) * 4 + (l15 - 12)) * 32 +
                (co2 * 4 + ct * 16 + quad);
            __hip_atomic_store(&mb[mbi], t.u, __ATOMIC_RELAXED,
                               __HIP_MEMORY_SCOPE_AGENT);
          }
        }
      }
    }
    pb ^= 1;
  }
}

// ---------------- launcher ---------------------------------------------------
extern "C" void kernel_launch(void* const* d_in, const int* in_sizes, int n_in,
                              void* d_out, int out_size, void* d_ws, size_t ws_size,
                              hipStream_t stream) {
  const float* x = (const float*)d_in[0];
  const float* K[4] = {(const float*)d_in[1], (const float*)d_in[2],
                       (const float*)d_in[3], (const float*)d_in[4]};
  float* out = (float*)d_out;

  char* ws = (char*)d_ws;
  float* y = (float*)ws;                       // 67,108,864 B
  int* flags = (int*)(ws + 67108864);          // 4*8*4 ints = 512 B
  u64* mb = (u64*)(ws + 67108864 + 1024);      // 8*4*2*2*4*128 bf16 = 262144 B

  hipMemsetAsync(flags, 0, 1024, stream);
  nchw_to_nhwc<<<B_ * HW_, 256, 0, stream>>>(x, y);

  const int PS[4] = {C_, C_, HW_ * C_, HW_ * C_};
  const int SS[4] = {HW_ * C_, HW_ * C_, C_, C_};
  const int S0[4] = {0, HW_ - 1, 0, HW_ - 1};
  const int DS[4] = {1, -1, 1, -1};
  for (int d = 0; d < 4; ++d)
    scnn_scan_dir<<<B_ * BLKS, THREADS, 0, stream>>>(K[d], y, flags, mb, PS[d],
                                                     SS[d], S0[d], DS[d], d);

  nhwc_to_nchw<<<B_ * HW_, 256, 0, stream>>>(y, out);
}

// Round 3
// 1986.156 us; speedup vs baseline: 1.6797x; 1.1187x over previous
//
#include <hip/hip_runtime.h>

#define B_   8
#define C_   128
#define HW_  128
#define KW_  9
#define BLKS 8               // blocks per batch (pos split)
#define POSB 16              // positions per block
#define ROWS 24              // 4 halo + 16 own + 4 halo
#define STRD 136             // LDS pos stride (elems)
#define BUFE (ROWS * STRD)   // 3264 elems per buffer
#define THREADS 512          // 8 waves, 2/SIMD

typedef __bf16 bf16x8 __attribute__((ext_vector_type(8)));
typedef float  floatx4 __attribute__((ext_vector_type(4)));
typedef unsigned long long u64;

__device__ __forceinline__ unsigned short bf16rn(float f) {
  union { float f; unsigned u; } x; x.f = f;
  return (unsigned short)((x.u + 0x7fffu + ((x.u >> 16) & 1u)) >> 16);
}

// ---------------- prologue: x (B,C,H,W) -> y (B,H,W,C) fp32 ------------------
__global__ __launch_bounds__(256) void nchw_to_nhwc(const float* __restrict__ x,
                                                    float* __restrict__ y) {
  __shared__ float tile[32][33];
  const int blk = blockIdx.x;
  const int b = blk >> 7, h = blk & 127;
  const int tx = threadIdx.x & 31, ty = threadIdx.x >> 5;
  for (int t = 0; t < 16; ++t) {
    const int c0 = (t >> 2) * 32, w0 = (t & 3) * 32;
#pragma unroll
    for (int i = 0; i < 4; ++i) {
      const int c = c0 + ty + i * 8;
      tile[ty + i * 8][tx] = x[(((long)b * C_ + c) * HW_ + h) * HW_ + w0 + tx];
    }
    __syncthreads();
#pragma unroll
    for (int i = 0; i < 4; ++i) {
      const int w = w0 + ty + i * 8;
      y[(((long)b * HW_ + h) * HW_ + w) * C_ + c0 + tx] = tile[tx][ty + i * 8];
    }
    __syncthreads();
  }
}

// ---------------- epilogue: y (B,H,W,C) -> out (B,C,H,W) ---------------------
__global__ __launch_bounds__(256) void nhwc_to_nchw(const float* __restrict__ y,
                                                    float* __restrict__ out) {
  __shared__ float tile[32][33];
  const int blk = blockIdx.x;
  const int b = blk >> 7, h = blk & 127;
  const int tx = threadIdx.x & 31, ty = threadIdx.x >> 5;
  for (int t = 0; t < 16; ++t) {
    const int w0 = (t >> 2) * 32, c0 = (t & 3) * 32;
#pragma unroll
    for (int i = 0; i < 4; ++i) {
      const int w = w0 + ty + i * 8;
      tile[ty + i * 8][tx] = y[(((long)b * HW_ + h) * HW_ + w) * C_ + c0 + tx];
    }
    __syncthreads();
#pragma unroll
    for (int i = 0; i < 4; ++i) {
      const int c = c0 + ty + i * 8;
      out[(((long)b * C_ + c) * HW_ + h) * HW_ + w0 + tx] = tile[tx][ty + i * 8];
    }
    __syncthreads();
  }
}

// ---------------- per-direction scan: 64 blocks = 8 batch x 8 pos-chunks -----
// 8 waves (2/SIMD). wave w = (kh = w>>2, co2 = w&3). Each wave computes TWO
// co-tiles (co2*16, co2*16+64) over HALF the K-fragments (c4 in {2kh, 2kh+1}):
// weights stay at 144 VGPR/wave, LDS B-frag reads = 144 b128 per block-row.
// kh=1 waves write fp32 partials to LDS scratch; kh=0 waves reduce + epilogue.
// Halo/flags via RELAXED agent atomics only; __syncthreads drains vmcnt(0) so
// mailbox stores are at the coherence point before tid0's relaxed flag store.
__global__ __launch_bounds__(THREADS, 2) void scnn_scan_dir(
    const float* __restrict__ Kg, float* __restrict__ y,
    int* flags, u64* mb,
    const int posStride, const int sStride, const int s0, const int ds,
    const int dirIdx) {
  __shared__ unsigned short prow[2][BUFE];
  __shared__ float scratch[4 * 2 * 64 * 4];  // [co2][ct][lane][4] = 8 KB
  const int tid = threadIdx.x;
  const int bid = blockIdx.x;
  const int batch = bid & 7;
  const int blk = bid >> 3;            // 0..7
  const int p0 = blk * POSB;
  const int lane = tid & 63;
  const int wave = tid >> 6;           // 0..7
  const int kh = wave >> 2;            // K-half: c4 in {2kh, 2kh+1}
  const int co2 = wave & 3;            // co-tile pair index
  const int l15 = lane & 15;
  const int quad = lane >> 4;
  const int ybase = batch * (HW_ * HW_ * C_);
  int* flagB = flags + (dirIdx * 8 + batch) * BLKS;

  // zero both LDS buffers (halo rows must read 0 for zero-pad conv)
  for (int i = tid; i < 2 * BUFE / 4; i += THREADS)
    ((u64*)prow)[i] = 0ull;

  // persistent weights, A-operand (m = co_local): 2 ct x 9 kw x 2 c2 = 144 VGPRs
  bf16x8 wfrag[2][KW_][2];
#pragma unroll
  for (int ct = 0; ct < 2; ++ct) {
    const int co0 = co2 * 16 + ct * 64;
#pragma unroll
    for (int kw = 0; kw < KW_; ++kw)
#pragma unroll
      for (int c2 = 0; c2 < 2; ++c2) {
        const int c4 = kh * 2 + c2;
        union { bf16x8 v; unsigned short u[8]; } t;
#pragma unroll
        for (int j = 0; j < 8; ++j)
          t.u[j] = bf16rn(Kg[(kw * 128 + c4 * 32 + quad * 8 + j) * 128 + co0 + l15]);
        wfrag[ct][kw][c2] = t.v;
      }
  }
  __syncthreads();

  // init: load first row (s0) 24-pos window (incl halo) from y -> buffer 0
  for (int i = tid; i < ROWS * 32; i += THREADS) {
    const int row = i >> 5, cg = i & 31;
    const int pos = p0 - 4 + row;
    if (pos >= 0 && pos < HW_) {
      const floatx4 v =
          *(const floatx4*)&y[ybase + s0 * sStride + pos * posStride + cg * 4];
      union { u64 u; unsigned short s[4]; } t;
      t.s[0] = bf16rn(v[0]); t.s[1] = bf16rn(v[1]);
      t.s[2] = bf16rn(v[2]); t.s[3] = bf16rn(v[3]);
      *(u64*)&prow[0][row * STRD + cg * 4] = t.u;
    }
  }
  __syncthreads();

  int pb = 0;
#pragma unroll 1
  for (int s = 1; s < HW_; ++s) {
    const int srow = s0 + s * ds;
    const int rowb = ybase + srow * sStride;

    __syncthreads();  // A: drains vmcnt -> step s-1 stores (incl mailbox) visible
    if (tid == 0)
      __hip_atomic_store(&flagB[blk], s - 1, __ATOMIC_RELAXED,
                         __HIP_MEMORY_SCOPE_AGENT);
    if (s >= 2) {
      if (tid == 0 && blk > 0)
        while (__hip_atomic_load(&flagB[blk - 1], __ATOMIC_RELAXED,
                                 __HIP_MEMORY_SCOPE_AGENT) < s - 1)
          __builtin_amdgcn_s_sleep(1);
      if (tid == 1 && blk < BLKS - 1)
        while (__hip_atomic_load(&flagB[blk + 1], __ATOMIC_RELAXED,
                                 __HIP_MEMORY_SCOPE_AGENT) < s - 1)
          __builtin_amdgcn_s_sleep(1);
      __syncthreads();  // P: poll done
      __atomic_signal_fence(__ATOMIC_SEQ_CST);
      const int par = (s - 1) & 1;
      if (tid < 256) {
        const int side = tid >> 7, p = (tid >> 5) & 3, cg = tid & 31;
        const bool doit = side ? (blk < BLKS - 1) : (blk > 0);
        if (doit) {
          const int srcB = side ? (blk + 1) : (blk - 1);
          const int srcSide = side ? 0 : 1;  // right halo = right nbr's L edge
          const int mbi =
              ((((batch * BLKS + srcB) * 2 + srcSide) * 2 + par) * 4 + p) * 32 + cg;
          const u64 v =
              __hip_atomic_load(&mb[mbi], __ATOMIC_RELAXED, __HIP_MEMORY_SCOPE_AGENT);
          const int row = side ? (20 + p) : p;   // right halo rows 20..23
          *(u64*)&prow[pb][row * STRD + cg * 4] = v;
        }
      }
    }
    __syncthreads();  // B: halo in LDS; prev buffer complete

    // cur-row prefetch (finisher waves only; overlaps the k-loop)
    floatx4 cur[2];
    if (kh == 0) {
#pragma unroll
      for (int ct = 0; ct < 2; ++ct)
        cur[ct] = *(const floatx4*)&y[rowb + (p0 + l15) * posStride +
                                      co2 * 16 + ct * 64 + quad * 4];
    }

    floatx4 acc[2];
    acc[0] = floatx4{0.f, 0.f, 0.f, 0.f};
    acc[1] = floatx4{0.f, 0.f, 0.f, 0.f};

    const unsigned short* pbase = &prow[pb][l15 * STRD + quad * 8];
#pragma unroll
    for (int kw = 0; kw < KW_; ++kw)
#pragma unroll
      for (int c2 = 0; c2 < 2; ++c2) {
        const int c4 = kh * 2 + c2;
        const bf16x8 b0 = *(const bf16x8*)(pbase + kw * STRD + c4 * 32);
        acc[0] = __builtin_amdgcn_mfma_f32_16x16x32_bf16(wfrag[0][kw][c2], b0,
                                                         acc[0], 0, 0, 0);
        acc[1] = __builtin_amdgcn_mfma_f32_16x16x32_bf16(wfrag[1][kw][c2], b0,
                                                         acc[1], 0, 0, 0);
      }

    // K-half reduction: kh=1 writes partials, kh=0 adds them
    if (kh == 1) {
#pragma unroll
      for (int ct = 0; ct < 2; ++ct)
        *(floatx4*)&scratch[((co2 * 2 + ct) * 64 + lane) * 4] = acc[ct];
    }
    __syncthreads();  // C: partials visible

    if (kh == 0) {
#pragma unroll
      for (int ct = 0; ct < 2; ++ct) {
        const floatx4 pz =
            *(const floatx4*)&scratch[((co2 * 2 + ct) * 64 + lane) * 4];
        acc[ct] += pz;
      }

      // epilogue: o = cur + relu(acc); fp32 -> y, bf16 -> nxt LDS (+ mailbox)
      unsigned short* nxt = prow[pb ^ 1];
      const int par_w = s & 1;
#pragma unroll
      for (int ct = 0; ct < 2; ++ct) {
        const int co0 = co2 * 16 + ct * 64;
        const int pl = l15;                    // local pos 0..15
        const int co = co0 + quad * 4;
        const floatx4 a = acc[ct];
        const floatx4 c = cur[ct];
        floatx4 o;
        o[0] = c[0] + (a[0] > 0.f ? a[0] : 0.f);
        o[1] = c[1] + (a[1] > 0.f ? a[1] : 0.f);
        o[2] = c[2] + (a[2] > 0.f ? a[2] : 0.f);
        o[3] = c[3] + (a[3] > 0.f ? a[3] : 0.f);
        *(floatx4*)&y[rowb + (p0 + pl) * posStride + co] = o;
        union { u64 u; unsigned short s[4]; } t;
        t.s[0] = bf16rn(o[0]); t.s[1] = bf16rn(o[1]);
        t.s[2] = bf16rn(o[2]); t.s[3] = bf16rn(o[3]);
        *(u64*)&nxt[(pl + 4) * STRD + co] = t.u;
        // boundary pos -> mailbox (relaxed agent atomics, bypass path)
        if (l15 < 4 && blk > 0) {
          const int mbi =
              ((((batch * BLKS + blk) * 2 + 0) * 2 + par_w) * 4 + l15) * 32 +
              (co2 * 4 + ct * 16 + quad);
          __hip_atomic_store(&mb[mbi], t.u, __ATOMIC_RELAXED,
                             __HIP_MEMORY_SCOPE_AGENT);
        }
        if (l15 >= 12 && blk < BLKS - 1) {
          const int mbi =
              ((((batch * BLKS + blk) * 2 + 1) * 2 + par_w) * 4 + (l15 - 12)) * 32 +
              (co2 * 4 + ct * 16 + quad);
          __hip_atomic_store(&mb[mbi], t.u, __ATOMIC_RELAXED,
                             __HIP_MEMORY_SCOPE_AGENT);
        }
      }
    }
    pb ^= 1;
  }
}

// ---------------- launcher ---------------------------------------------------
extern "C" void kernel_launch(void* const* d_in, const int* in_sizes, int n_in,
                              void* d_out, int out_size, void* d_ws, size_t ws_size,
                              hipStream_t stream) {
  const float* x = (const float*)d_in[0];
  const float* K[4] = {(const float*)d_in[1], (const float*)d_in[2],
                       (const float*)d_in[3], (const float*)d_in[4]};
  float* out = (float*)d_out;

  char* ws = (char*)d_ws;
  float* y = (float*)ws;                       // 67,108,864 B
  int* flags = (int*)(ws + 67108864);          // 4*8*8 ints = 1024 B
  u64* mb = (u64*)(ws + 67108864 + 1024);      // 8*8*2*2*4*32 u64 = 262144 B

  hipMemsetAsync(flags, 0, 1024, stream);
  nchw_to_nhwc<<<B_ * HW_, 256, 0, stream>>>(x, y);

  const int PS[4] = {C_, C_, HW_ * C_, HW_ * C_};
  const int SS[4] = {HW_ * C_, HW_ * C_, C_, C_};
  const int S0[4] = {0, HW_ - 1, 0, HW_ - 1};
  const int DS[4] = {1, -1, 1, -1};
  for (int d = 0; d < 4; ++d)
    scnn_scan_dir<<<B_ * BLKS, THREADS, 0, stream>>>(K[d], y, flags, mb, PS[d],
                                                     SS[d], S0[d], DS[d], d);

  nhwc_to_nchw<<<B_ * HW_, 256, 0, stream>>>(y, out);
}

// Round 4
// 1939.681 us; speedup vs baseline: 1.7200x; 1.0240x over previous
//
#include <hip/hip_runtime.h>

#define B_   8
#define C_   128
#define HW_  128
#define KW_  9
#define BLKS 8               // blocks per batch (pos split)
#define POSB 16              // positions per block
#define ROWS 24              // 4 halo + 16 own + 4 halo
#define STRD 136             // LDS pos stride (elems)
#define BUFE (ROWS * STRD)   // 3264 elems per buffer
#define THREADS 512          // 8 waves, 2/SIMD

typedef __bf16 bf16x8 __attribute__((ext_vector_type(8)));
typedef float  floatx4 __attribute__((ext_vector_type(4)));
typedef unsigned long long u64;

__device__ __forceinline__ unsigned short bf16rn(float f) {
  union { float f; unsigned u; } x; x.f = f;
  return (unsigned short)((x.u + 0x7fffu + ((x.u >> 16) & 1u)) >> 16);
}

// ---------------- prologue: x (B,C,H,W) -> y (B,H,W,C) fp32 ------------------
__global__ __launch_bounds__(256) void nchw_to_nhwc(const float* __restrict__ x,
                                                    float* __restrict__ y) {
  __shared__ float tile[32][33];
  const int blk = blockIdx.x;
  const int b = blk >> 7, h = blk & 127;
  const int tx = threadIdx.x & 31, ty = threadIdx.x >> 5;
  for (int t = 0; t < 16; ++t) {
    const int c0 = (t >> 2) * 32, w0 = (t & 3) * 32;
#pragma unroll
    for (int i = 0; i < 4; ++i) {
      const int c = c0 + ty + i * 8;
      tile[ty + i * 8][tx] = x[(((long)b * C_ + c) * HW_ + h) * HW_ + w0 + tx];
    }
    __syncthreads();
#pragma unroll
    for (int i = 0; i < 4; ++i) {
      const int w = w0 + ty + i * 8;
      y[(((long)b * HW_ + h) * HW_ + w) * C_ + c0 + tx] = tile[tx][ty + i * 8];
    }
    __syncthreads();
  }
}

// ---------------- epilogue: y (B,H,W,C) -> out (B,C,H,W) ---------------------
__global__ __launch_bounds__(256) void nhwc_to_nchw(const float* __restrict__ y,
                                                    float* __restrict__ out) {
  __shared__ float tile[32][33];
  const int blk = blockIdx.x;
  const int b = blk >> 7, h = blk & 127;
  const int tx = threadIdx.x & 31, ty = threadIdx.x >> 5;
  for (int t = 0; t < 16; ++t) {
    const int w0 = (t >> 2) * 32, c0 = (t & 3) * 32;
#pragma unroll
    for (int i = 0; i < 4; ++i) {
      const int w = w0 + ty + i * 8;
      tile[ty + i * 8][tx] = y[(((long)b * HW_ + h) * HW_ + w) * C_ + c0 + tx];
    }
    __syncthreads();
#pragma unroll
    for (int i = 0; i < 4; ++i) {
      const int c = c0 + ty + i * 8;
      out[(((long)b * C_ + c) * HW_ + h) * HW_ + w0 + tx] = tile[tx][ty + i * 8];
    }
    __syncthreads();
  }
}

// ---------------- per-direction scan: 64 blocks = 8 batch x 8 pos-chunks -----
// Zero-halo main compute + halo-correction MFMAs:
//   prow halo rows (0..3, 20..23) are PERMANENTLY ZERO. Main k-loop runs
//   immediately after barrier A (no neighbor wait). Comm waves (7=left,
//   6=right) run main first, then poll neighbor flag + load mailbox into the
//   hal region (RT hidden under the other waves' main loops). After barrier H,
//   all waves apply correction MFMAs: left kw 0..3 uses halL[l15+kw] when
//   l15+kw<=3 (else broadcast zero16); right kw 5..8 uses halR[l15+kw-20].
// Halo/flags via RELAXED agent atomics only; __syncthreads drains vmcnt(0) so
// mailbox stores are at the coherence point before tid0's relaxed flag store.
__global__ __launch_bounds__(THREADS, 2) void scnn_scan_dir(
    const float* __restrict__ Kg, float* __restrict__ y,
    int* flags, u64* mb,
    const int posStride, const int sStride, const int s0, const int ds,
    const int dirIdx) {
  __shared__ unsigned short prow[2][BUFE];
  __shared__ unsigned short halL[4 * 128];   // left halo rows (global pos p0-4..p0-1)
  __shared__ unsigned short halR[4 * 128];   // right halo rows (p0+16..p0+19)
  __shared__ unsigned short z16[8];          // broadcast zero fragment
  __shared__ float scratch[4 * 2 * 64 * 4];  // [co2][ct][lane][4] = 8 KB
  const int tid = threadIdx.x;
  const int bid = blockIdx.x;
  const int batch = bid & 7;
  const int blk = bid >> 3;            // 0..7
  const int p0 = blk * POSB;
  const int lane = tid & 63;
  const int wave = tid >> 6;           // 0..7
  const int kh = wave >> 2;            // K-half: c4 in {2kh, 2kh+1}
  const int co2 = wave & 3;            // co-tile pair index
  const int l15 = lane & 15;
  const int quad = lane >> 4;
  const int ybase = batch * (HW_ * HW_ * C_);
  int* flagB = flags + (dirIdx * 8 + batch) * BLKS;

  // zero LDS: prow (halo rows must stay 0), hal regions, z16
  for (int i = tid; i < 2 * BUFE / 4; i += THREADS)
    ((u64*)prow)[i] = 0ull;
  for (int i = tid; i < (4 * 128 * 2 + 8) / 4; i += THREADS)
    ((u64*)halL)[i] = 0ull;   // halL, halR, z16 are contiguous enough? no — zero each
  for (int i = tid; i < 4 * 128 / 4; i += THREADS) ((u64*)halR)[i] = 0ull;
  if (tid < 2) ((u64*)z16)[tid] = 0ull;

  // persistent weights, A-operand (m = co_local): 2 ct x 9 kw x 2 c2 = 144 VGPRs
  bf16x8 wfrag[2][KW_][2];
#pragma unroll
  for (int ct = 0; ct < 2; ++ct) {
    const int co0 = co2 * 16 + ct * 64;
#pragma unroll
    for (int kw = 0; kw < KW_; ++kw)
#pragma unroll
      for (int c2 = 0; c2 < 2; ++c2) {
        const int c4 = kh * 2 + c2;
        union { bf16x8 v; unsigned short u[8]; } t;
#pragma unroll
        for (int j = 0; j < 8; ++j)
          t.u[j] = bf16rn(Kg[(kw * 128 + c4 * 32 + quad * 8 + j) * 128 + co0 + l15]);
        wfrag[ct][kw][c2] = t.v;
      }
  }
  __syncthreads();

  // init: first row (s0). Own rows -> prow[0] rows 4..19; halo -> halL/halR.
  for (int i = tid; i < ROWS * 32; i += THREADS) {
    const int row = i >> 5, cg = i & 31;
    const int pos = p0 - 4 + row;
    if (pos >= 0 && pos < HW_) {
      const floatx4 v =
          *(const floatx4*)&y[ybase + s0 * sStride + pos * posStride + cg * 4];
      union { u64 u; unsigned short s[4]; } t;
      t.s[0] = bf16rn(v[0]); t.s[1] = bf16rn(v[1]);
      t.s[2] = bf16rn(v[2]); t.s[3] = bf16rn(v[3]);
      if (row < 4)
        *(u64*)&halL[row * 128 + cg * 4] = t.u;
      else if (row >= 20)
        *(u64*)&halR[(row - 20) * 128 + cg * 4] = t.u;
      else
        *(u64*)&prow[0][row * STRD + cg * 4] = t.u;
    }
  }
  __syncthreads();

  int pb = 0;
#pragma unroll 1
  for (int s = 1; s < HW_; ++s) {
    const int srow = s0 + s * ds;
    const int rowb = ybase + srow * sStride;

    __syncthreads();  // A: dbuf swap; drains vmcnt -> s-1 mailbox stores visible
    if (tid == 0)
      __hip_atomic_store(&flagB[blk], s - 1, __ATOMIC_RELAXED,
                         __HIP_MEMORY_SCOPE_AGENT);

    // cur-row prefetch (finisher waves; overlaps the k-loop)
    floatx4 cur[2];
    if (kh == 0) {
#pragma unroll
      for (int ct = 0; ct < 2; ++ct)
        cur[ct] = *(const floatx4*)&y[rowb + (p0 + l15) * posStride +
                                      co2 * 16 + ct * 64 + quad * 4];
    }

    // ---- main k-loop on zero-halo prow (no neighbor dependency) ----
    floatx4 acc[2];
    acc[0] = floatx4{0.f, 0.f, 0.f, 0.f};
    acc[1] = floatx4{0.f, 0.f, 0.f, 0.f};
    const unsigned short* pbase = &prow[pb][l15 * STRD + quad * 8];
#pragma unroll
    for (int kw = 0; kw < KW_; ++kw)
#pragma unroll
      for (int c2 = 0; c2 < 2; ++c2) {
        const int c4 = kh * 2 + c2;
        const bf16x8 b0 = *(const bf16x8*)(pbase + kw * STRD + c4 * 32);
        acc[0] = __builtin_amdgcn_mfma_f32_16x16x32_bf16(wfrag[0][kw][c2], b0,
                                                         acc[0], 0, 0, 0);
        acc[1] = __builtin_amdgcn_mfma_f32_16x16x32_bf16(wfrag[1][kw][c2], b0,
                                                         acc[1], 0, 0, 0);
      }

    // ---- comm (waves 6/7): poll neighbor flag, mailbox -> hal ----
    if (s >= 2) {
      const int par = (s - 1) & 1;
      if (wave == 7 && blk > 0) {
        if (lane == 0)
          while (__hip_atomic_load(&flagB[blk - 1], __ATOMIC_RELAXED,
                                   __HIP_MEMORY_SCOPE_AGENT) < s - 1)
            __builtin_amdgcn_s_sleep(1);
        __atomic_signal_fence(__ATOMIC_SEQ_CST);
        const int base = ((((batch * BLKS + (blk - 1)) * 2 + 1) * 2 + par) * 4) * 32;
        const u64 v0 = __hip_atomic_load(&mb[base + lane], __ATOMIC_RELAXED,
                                         __HIP_MEMORY_SCOPE_AGENT);
        const u64 v1 = __hip_atomic_load(&mb[base + 64 + lane], __ATOMIC_RELAXED,
                                         __HIP_MEMORY_SCOPE_AGENT);
        *(u64*)&halL[(lane >> 5) * 128 + (lane & 31) * 4] = v0;
        *(u64*)&halL[(2 + (lane >> 5)) * 128 + (lane & 31) * 4] = v1;
      }
      if (wave == 6 && blk < BLKS - 1) {
        if (lane == 0)
          while (__hip_atomic_load(&flagB[blk + 1], __ATOMIC_RELAXED,
                                   __HIP_MEMORY_SCOPE_AGENT) < s - 1)
            __builtin_amdgcn_s_sleep(1);
        __atomic_signal_fence(__ATOMIC_SEQ_CST);
        const int base = ((((batch * BLKS + (blk + 1)) * 2 + 0) * 2 + par) * 4) * 32;
        const u64 v0 = __hip_atomic_load(&mb[base + lane], __ATOMIC_RELAXED,
                                         __HIP_MEMORY_SCOPE_AGENT);
        const u64 v1 = __hip_atomic_load(&mb[base + 64 + lane], __ATOMIC_RELAXED,
                                         __HIP_MEMORY_SCOPE_AGENT);
        *(u64*)&halR[(lane >> 5) * 128 + (lane & 31) * 4] = v0;
        *(u64*)&halR[(2 + (lane >> 5)) * 128 + (lane & 31) * 4] = v1;
      }
    }
    __syncthreads();  // H: hal ready for corrections

    // ---- halo correction MFMAs ----
    if (blk > 0) {
#pragma unroll
      for (int kw = 0; kw < 4; ++kw) {
        const int hr = l15 + kw;               // buffer row; halo iff <= 3
        const bool v = hr <= 3;
#pragma unroll
        for (int c2 = 0; c2 < 2; ++c2) {
          const int c4 = kh * 2 + c2;
          const unsigned short* sp =
              v ? &halL[hr * 128 + c4 * 32 + quad * 8] : z16;
          const bf16x8 b = *(const bf16x8*)sp;
          acc[0] = __builtin_amdgcn_mfma_f32_16x16x32_bf16(wfrag[0][kw][c2], b,
                                                           acc[0], 0, 0, 0);
          acc[1] = __builtin_amdgcn_mfma_f32_16x16x32_bf16(wfrag[1][kw][c2], b,
                                                           acc[1], 0, 0, 0);
        }
      }
    }
    if (blk < BLKS - 1) {
#pragma unroll
      for (int kw = 5; kw < 9; ++kw) {
        const int hr = l15 + kw - 20;          // halR row; valid iff >= 0
        const bool v = hr >= 0;
#pragma unroll
        for (int c2 = 0; c2 < 2; ++c2) {
          const int c4 = kh * 2 + c2;
          const unsigned short* sp =
              v ? &halR[hr * 128 + c4 * 32 + quad * 8] : z16;
          const bf16x8 b = *(const bf16x8*)sp;
          acc[0] = __builtin_amdgcn_mfma_f32_16x16x32_bf16(wfrag[0][kw][c2], b,
                                                           acc[0], 0, 0, 0);
          acc[1] = __builtin_amdgcn_mfma_f32_16x16x32_bf16(wfrag[1][kw][c2], b,
                                                           acc[1], 0, 0, 0);
        }
      }
    }

    // K-half reduction: kh=1 writes partials, kh=0 adds them
    if (kh == 1) {
#pragma unroll
      for (int ct = 0; ct < 2; ++ct)
        *(floatx4*)&scratch[((co2 * 2 + ct) * 64 + lane) * 4] = acc[ct];
    }
    __syncthreads();  // C: partials visible

    if (kh == 0) {
#pragma unroll
      for (int ct = 0; ct < 2; ++ct) {
        const floatx4 pz =
            *(const floatx4*)&scratch[((co2 * 2 + ct) * 64 + lane) * 4];
        acc[ct] += pz;
      }

      // epilogue: o = cur + relu(acc); fp32 -> y, bf16 -> nxt LDS (+ mailbox)
      unsigned short* nxt = prow[pb ^ 1];
      const int par_w = s & 1;
#pragma unroll
      for (int ct = 0; ct < 2; ++ct) {
        const int co0 = co2 * 16 + ct * 64;
        const int pl = l15;                    // local pos 0..15
        const int co = co0 + quad * 4;
        const floatx4 a = acc[ct];
        const floatx4 c = cur[ct];
        floatx4 o;
        o[0] = c[0] + (a[0] > 0.f ? a[0] : 0.f);
        o[1] = c[1] + (a[1] > 0.f ? a[1] : 0.f);
        o[2] = c[2] + (a[2] > 0.f ? a[2] : 0.f);
        o[3] = c[3] + (a[3] > 0.f ? a[3] : 0.f);
        *(floatx4*)&y[rowb + (p0 + pl) * posStride + co] = o;
        union { u64 u; unsigned short s[4]; } t;
        t.s[0] = bf16rn(o[0]); t.s[1] = bf16rn(o[1]);
        t.s[2] = bf16rn(o[2]); t.s[3] = bf16rn(o[3]);
        *(u64*)&nxt[(pl + 4) * STRD + co] = t.u;
        // boundary pos -> mailbox (relaxed agent atomics, bypass path)
        if (l15 < 4 && blk > 0) {
          const int mbi =
              ((((batch * BLKS + blk) * 2 + 0) * 2 + par_w) * 4 + l15) * 32 +
              (co2 * 4 + ct * 16 + quad);
          __hip_atomic_store(&mb[mbi], t.u, __ATOMIC_RELAXED,
                             __HIP_MEMORY_SCOPE_AGENT);
        }
        if (l15 >= 12 && blk < BLKS - 1) {
          const int mbi =
              ((((batch * BLKS + blk) * 2 + 1) * 2 + par_w) * 4 + (l15 - 12)) * 32 +
              (co2 * 4 + ct * 16 + quad);
          __hip_atomic_store(&mb[mbi], t.u, __ATOMIC_RELAXED,
                             __HIP_MEMORY_SCOPE_AGENT);
        }
      }
    }
    pb ^= 1;
  }
}

// ---------------- launcher ---------------------------------------------------
extern "C" void kernel_launch(void* const* d_in, const int* in_sizes, int n_in,
                              void* d_out, int out_size, void* d_ws, size_t ws_size,
                              hipStream_t stream) {
  const float* x = (const float*)d_in[0];
  const float* K[4] = {(const float*)d_in[1], (const float*)d_in[2],
                       (const float*)d_in[3], (const float*)d_in[4]};
  float* out = (float*)d_out;

  char* ws = (char*)d_ws;
  float* y = (float*)ws;                       // 67,108,864 B
  int* flags = (int*)(ws + 67108864);          // 4*8*8 ints = 1024 B
  u64* mb = (u64*)(ws + 67108864 + 1024);      // 8*8*2*2*4*32 u64 = 262144 B

  hipMemsetAsync(flags, 0, 1024, stream);
  nchw_to_nhwc<<<B_ * HW_, 256, 0, stream>>>(x, y);

  const int PS[4] = {C_, C_, HW_ * C_, HW_ * C_};
  const int SS[4] = {HW_ * C_, HW_ * C_, C_, C_};
  const int S0[4] = {0, HW_ - 1, 0, HW_ - 1};
  const int DS[4] = {1, -1, 1, -1};
  for (int d = 0; d < 4; ++d)
    scnn_scan_dir<<<B_ * BLKS, THREADS, 0, stream>>>(K[d], y, flags, mb, PS[d],
                                                     SS[d], S0[d], DS[d], d);

  nhwc_to_nchw<<<B_ * HW_, 256, 0, stream>>>(y, out);
}